// Round 3
// baseline (580.052 us; speedup 1.0000x reference)
//
#include <hip/hip_runtime.h>

typedef __bf16 bf16x8 __attribute__((ext_vector_type(8)));
typedef float f32x4 __attribute__((ext_vector_type(4)));
typedef unsigned short ushort8 __attribute__((ext_vector_type(8)));

__device__ __forceinline__ unsigned short f2b(float f) {
    unsigned int u = __float_as_uint(f);
    return (unsigned short)((u + 0x7fffu + ((u >> 16) & 1u)) >> 16);  // RNE
}

// ---------------------------------------------------------------------------
// Prep: fold W_nl into W_out, emit bf16 W' in MFMA B-fragment order, and the
// fused bias b'[o] = b_out[o] + sum_f b_nl[f]*W_out[o,f].
// Flat index t = (((ct*8 + ks)*64 + lane)*8 + j) holds
//   B[k = ks*32 + (lane>>4)*8 + j][n = ct*16 + (lane&15)],  ct = 0..15
// with B[f][o] = s*(W_nl[f,0]+W_nl[f,1]) * W_out[o,f].
// ---------------------------------------------------------------------------
__global__ __launch_bounds__(256) void wk_prep(
    const float* __restrict__ Wnl, const float* __restrict__ bnl,
    const float* __restrict__ Wout, const float* __restrict__ bout,
    unsigned short* __restrict__ wfrag, float* __restrict__ wbias) {
    int b = blockIdx.x, tid = threadIdx.x;
    if (b < 256) {
        int t = b * 256 + tid;
        int j = t & 7;
        int lane = (t >> 3) & 63;
        int ks = (t >> 9) & 7;
        int ct = t >> 12;                       // global col-tile 0..15
        int f = ks * 32 + ((lane >> 4) << 3) + j;
        int o = ct * 16 + (lane & 15);
        float c = 0.70710678f * (Wnl[2 * f] + Wnl[2 * f + 1]);
        wfrag[t] = f2b(c * Wout[o * 256 + f]);
    } else {
        int o = tid;
        float s = 0.f;
        #pragma unroll 8
        for (int f = 0; f < 256; ++f) s += bnl[f] * Wout[o * 256 + f];
        wbias[o] = bout[o] + s;
    }
}

// ---------------------------------------------------------------------------
// Main GEMM: M=160000, K=256, N=256, persistent-pipelined.
// Grid = 256 blocks x 512 thr (8 waves); 128 KB LDS = full W' -> 1 block/CU.
// W' staged once, ONE barrier total. Each wave grid-strides over 16-row
// tiles (10000 tiles / 2048 waves): convert tile t, issue tile t+1 loads,
// then 16 col-tiles x 8 K-steps of MFMA. Loads stay in flight across the
// MFMA phase (vmcnt FIFO: loads issued before stores), so HBM never drains.
// ---------------------------------------------------------------------------
__global__ __launch_bounds__(512) void wk_main(
    const float* __restrict__ x, const unsigned short* __restrict__ wfrag,
    const float* __restrict__ wbias, float* __restrict__ out) {
    const int tid  = threadIdx.x;
    const int lane = tid & 63;
    const int w    = tid >> 6;          // wave 0..7
    const int m    = lane & 15;
    const int quad = lane >> 4;

    __shared__ bf16x8 Wlds[8192];       // 128 KB: [ct(16)][ks(8)][lane(64)] x 8 bf16

    // --- stage full W' into LDS (coalesced 16B copies, once per block) ---
    {
        int4* dst = (int4*)Wlds;
        const int4* src = (const int4*)wfrag;
        #pragma unroll
        for (int i = 0; i < 16; ++i) dst[tid + i * 512] = src[tid + i * 512];
    }

    // --- per-lane fused bias for my column in each of 16 col-tiles ---
    float bias_r[16];
    #pragma unroll
    for (int ct = 0; ct < 16; ++ct) bias_r[ct] = wbias[ct * 16 + m];

    __syncthreads();                    // the only barrier

    const int NT = 10000;               // 16-row tiles (160000 rows)
    const int stride = 2048;            // total waves in grid
    int t = blockIdx.x * 8 + w;

    // --- prologue: issue first tile's x loads (16 rows x K=256, 32 B/lane) ---
    float4 raw[16];
    {
        const float4* xv = (const float4*)(x) + (size_t)t * 1024 + m * 64 + quad * 2;
        #pragma unroll
        for (int ks = 0; ks < 8; ++ks) {
            raw[2 * ks]     = xv[ks * 8];
            raw[2 * ks + 1] = xv[ks * 8 + 1];
        }
    }

    while (t < NT) {
        // convert current tile -> A fragments (A[m=lane&15][k=quad*8+j])
        bf16x8 afr[8];
        #pragma unroll
        for (int ks = 0; ks < 8; ++ks) {
            float4 u = raw[2 * ks], v = raw[2 * ks + 1];
            ushort8 s;
            s[0] = f2b(u.x); s[1] = f2b(u.y); s[2] = f2b(u.z); s[3] = f2b(u.w);
            s[4] = f2b(v.x); s[5] = f2b(v.y); s[6] = f2b(v.z); s[7] = f2b(v.w);
            afr[ks] = __builtin_bit_cast(bf16x8, s);
        }

        // prefetch next tile (in flight during the MFMA phase below)
        int tn = t + stride;
        if (tn < NT) {
            const float4* xv = (const float4*)(x) + (size_t)tn * 1024 + m * 64 + quad * 2;
            #pragma unroll
            for (int ks = 0; ks < 8; ++ks) {
                raw[2 * ks]     = xv[ks * 8];
                raw[2 * ks + 1] = xv[ks * 8 + 1];
            }
        }

        // 16 col-tiles x 8 K-steps, bias-initialized accumulators
        size_t rbase = ((size_t)t * 16 + quad * 4) * 256;
        #pragma unroll
        for (int ct = 0; ct < 16; ++ct) {
            f32x4 acc = {bias_r[ct], bias_r[ct], bias_r[ct], bias_r[ct]};
            #pragma unroll
            for (int ks = 0; ks < 8; ++ks) {
                acc = __builtin_amdgcn_mfma_f32_16x16x32_bf16(
                    afr[ks], Wlds[(ct * 8 + ks) * 64 + lane], acc, 0, 0, 0);
            }
            // D layout: row = quad*4 + i, col = ct*16 + (lane&15)
            size_t base = rbase + ct * 16 + m;
            out[base]       = acc[0];
            out[base + 256] = acc[1];
            out[base + 512] = acc[2];
            out[base + 768] = acc[3];
        }
        t = tn;
    }
}

extern "C" void kernel_launch(void* const* d_in, const int* in_sizes, int n_in,
                              void* d_out, int out_size, void* d_ws, size_t ws_size,
                              hipStream_t stream) {
    const float* x    = (const float*)d_in[0];   // [8,20000,256]
    const float* Wnl  = (const float*)d_in[1];   // [256,2]
    const float* bnl  = (const float*)d_in[2];   // [256]
    const float* Wout = (const float*)d_in[3];   // [256,256]
    const float* bout = (const float*)d_in[4];   // [256]

    unsigned short* wfrag = (unsigned short*)d_ws;            // 65536 bf16 = 128 KB
    float* wbias = (float*)((char*)d_ws + 131072);            // 256 f32

    wk_prep<<<257, 256, 0, stream>>>(Wnl, bnl, Wout, bout, wfrag, wbias);
    wk_main<<<256, 512, 0, stream>>>(x, wfrag, wbias, (float*)d_out);
}